// Round 8
// baseline (256.545 us; speedup 1.0000x reference)
//
#include <hip/hip_runtime.h>
#include <math.h>

// Problem constants
#define BB    2
#define SS    384
#define DD    128
#define NH    8
#define HDIM  16
#define NBH   16      // B*H
#define BS    768     // B*S

typedef unsigned int   u32;
typedef unsigned short u16;
typedef __attribute__((ext_vector_type(8))) short short8;
typedef __attribute__((ext_vector_type(4))) float f32x4;

// ---------------- compile-time Cl(4,1) geometric-product sign table ----------
struct SignTab { float v[32][32]; };
constexpr int popcnt32c(int x){ int c=0; for(int i=0;i<32;i++) c += (x>>i)&1; return c; }
constexpr int signgp_int(int a, int b){
  int swaps=0; int aa=a>>1;
  while(aa){ swaps += popcnt32c(aa & b); aa >>= 1; }
  int s = (swaps & 1) ? -1 : 1;
  if ((a & b) & 16) s = -s;   // e5 (bit 4) squares to -1
  return s;
}
constexpr SignTab make_signs(){
  SignTab t{};
  for(int a=0;a<32;a++) for(int b=0;b<32;b++)
    t.v[a][b] = (float)signgp_int(a,b);
  return t;
}
constexpr SignTab GPS = make_signs();

// Sign-bit XOR masks for scores B fragment, blade c=(w<<3)|u.
struct MaskTab { u32 v[4][8][4][4]; };
constexpr MaskTab mkmask(){
  MaskTab t{};
  for(int w=0;w<4;w++) for(int u=0;u<8;u++) for(int q=0;q<4;q++) for(int r=0;r<4;r++){
    u32 m = 0;
    for(int h=0;h<2;h++){
      int j = 2*r + h;
      int i = (q<<3) | j;
      int c = (w<<3) | u;
      if (signgp_int(i, i^c) < 0) m |= (h ? 0x80000000u : 0x8000u);
    }
    t.v[w][u][q][r] = m;
  }
  return t;
}
constexpr MaskTab MT = mkmask();

__device__ __forceinline__ u16 f2bf(float f){   // round-to-nearest-even
  u32 x = __float_as_uint(f);
  return (u16)((x + 0x7FFFu + ((x>>16)&1u)) >> 16);
}
__device__ __forceinline__ float bf2f(u16 h){
  return __uint_as_float(((u32)h) << 16);
}

// ---------------- blade gather (y=0) + weight repack (y=1) -------------------
#define XLS 33
__global__ __launch_bounds__(256) void gather_k(const float* __restrict__ src,
                                                u16* __restrict__ xg,
                                                const float* __restrict__ wq,
                                                const float* __restrict__ wk,
                                                const float* __restrict__ wv,
                                                const float* __restrict__ wo,
                                                u16* __restrict__ wpk2){
  if (blockIdx.y == 1){
    int idx = blockIdx.x*256 + threadIdx.x;      // 0..98303
    int o   = idx / 768;
    int rem = idx - o*768;
    int jp  = rem >> 7;
    int i   = rem & 127;
    const int SV[6] = {0,1,2,4,8,16};
    const float* ww[4] = {wq, wk, wv, wo};
    #pragma unroll
    for(int p=0;p<4;p++)
      wpk2[p*98304 + idx] = f2bf(ww[p][(o*128 + i)*32 + SV[jp]]);
    return;
  }

  __shared__ float xl[2*128*XLS];
  int t = threadIdx.x;
  int bs0 = blockIdx.x*2;
  int bsl = t >> 7, i = t & 127;

  float row[32];
  const float4* s4 = (const float4*)(src + (((size_t)(bs0+bsl)*128 + i)*32));
  #pragma unroll
  for(int r=0;r<8;r++){
    float4 v = s4[r];
    row[r*4+0]=v.x; row[r*4+1]=v.y; row[r*4+2]=v.z; row[r*4+3]=v.w;
  }
  float* xrow = xl + bsl*128*XLS + i*XLS;
  #pragma unroll
  for(int l=0;l<32;l++) xrow[l] = row[l];
  __syncthreads();

  const int SV[6] = {0,1,2,4,8,16};
  u32* xg32 = (u32*)xg;
  #pragma unroll 4
  for(int r=0;r<96;r++){
    int wr = t + r*256;
    int k   = wr / 768;
    int rem = wr - k*768;
    int bl  = rem / 384;
    int r2  = rem - bl*384;
    int jp  = r2 >> 6;
    int ip  = r2 & 63;
    int i2  = ip*2;
    int b   = SV[jp] ^ k;
    float sg = GPS.v[SV[jp]][b];
    const float* base = xl + bl*128*XLS;
    float f0 = base[ i2   *XLS + b] * sg;
    float f1 = base[(i2+1)*XLS + b] * sg;
    u32 pk = (u32)f2bf(f0) | ((u32)f2bf(f1) << 16);
    xg32[((size_t)k*768 + bs0 + bl)*384 + jp*64 + ip] = pk;
  }
}

// ---------------- projection GEMM --------------------------------------------
#define LSTR 40
__global__ __launch_bounds__(256) void gemm_proj(const u16* __restrict__ xg,
                                                 const u16* __restrict__ wpkA,
                                                 u16* __restrict__ tmpA){
  __shared__ __align__(16) u16 As[128*LSTR];
  __shared__ __align__(16) u16 Bs[128*LSTR];
  int t = threadIdx.x;
  int Mt = blockIdx.x, k = blockIdx.y, p = blockIdx.z;
  const u16* wpk = wpkA + (size_t)p*98304;
  u16* tmp = tmpA + (size_t)p*32*768*128;

  int w = t >> 6, lane = t & 63;
  int q = lane >> 4, n16 = lane & 15;
  int wm = w >> 1, wn = w & 1;

  f32x4 acc[4][4];
  #pragma unroll
  for(int a=0;a<4;a++)
    #pragma unroll
    for(int b=0;b<4;b++) acc[a][b] = (f32x4){0.f,0.f,0.f,0.f};

  int r0 = t>>2, c0 = (t&3)*8;
  int r1 = (t+256)>>2, c1 = ((t+256)&3)*8;
  const u16* Aab = xg + ((size_t)k*768 + Mt*128)*768;

  uint4 pa0, pa1, pb0, pb1;
  {
    pa0 = *(const uint4*)(Aab + (size_t)r0*768 + c0);
    pa1 = *(const uint4*)(Aab + (size_t)r1*768 + c1);
    pb0 = *(const uint4*)(wpk + (size_t)r0*768 + c0);
    pb1 = *(const uint4*)(wpk + (size_t)r1*768 + c1);
  }

  for(int kt=0; kt<24; kt++){
    __syncthreads();
    *(uint4*)(As + r0*LSTR + c0) = pa0;
    *(uint4*)(As + r1*LSTR + c1) = pa1;
    *(uint4*)(Bs + r0*LSTR + c0) = pb0;
    *(uint4*)(Bs + r1*LSTR + c1) = pb1;
    __syncthreads();
    if (kt < 23){
      int kn = (kt+1)*32;
      pa0 = *(const uint4*)(Aab + (size_t)r0*768 + kn + c0);
      pa1 = *(const uint4*)(Aab + (size_t)r1*768 + kn + c1);
      pb0 = *(const uint4*)(wpk + (size_t)r0*768 + kn + c0);
      pb1 = *(const uint4*)(wpk + (size_t)r1*768 + kn + c1);
    }
    short8 a[4], b[4];
    #pragma unroll
    for(int mi=0;mi<4;mi++)
      a[mi] = *(const short8*)(As + (wm*64 + mi*16 + n16)*LSTR + q*8);
    #pragma unroll
    for(int ni=0;ni<4;ni++)
      b[ni] = *(const short8*)(Bs + (wn*64 + ni*16 + n16)*LSTR + q*8);
    #pragma unroll
    for(int mi=0;mi<4;mi++)
      #pragma unroll
      for(int ni=0;ni<4;ni++)
        acc[mi][ni] = __builtin_amdgcn_mfma_f32_16x16x32_bf16(a[mi], b[ni], acc[mi][ni], 0,0,0);
  }

  #pragma unroll
  for(int mi=0;mi<4;mi++){
    #pragma unroll
    for(int r=0;r<4;r++){
      int m = Mt*128 + wm*64 + mi*16 + q*4 + r;
      #pragma unroll
      for(int ni=0;ni<4;ni++){
        int n = wn*64 + ni*16 + n16;
        tmp[((size_t)k*768 + m)*128 + n] = f2bf(acc[mi][ni][r]);
      }
    }
  }
}

// ---------------- normalize + head-split for Q,K,V (one dispatch) ------------
__global__ __launch_bounds__(256) void norm3(const u16* __restrict__ tmpA,
                                             u16* __restrict__ qhb,
                                             u16* __restrict__ khb,
                                             u16* __restrict__ vbb){
  int z = blockIdx.y;
  const u16* tmp = tmpA + (size_t)z*32*768*128;
  u16* dst = (z==0)?qhb:(z==1)?khb:vbb;
  int t = threadIdx.x;
  int bsl = t >> 7, o = t & 127;
  int bs = blockIdx.x*2 + bsl;

  float a[32];
  float ssum = 1e-8f;
  #pragma unroll
  for(int k=0;k<32;k++){
    a[k] = bf2f(tmp[((size_t)k*768 + bs)*128 + o]);
    ssum = fmaf(a[k], a[k], ssum);
  }
  float inv = 1.0f / sqrtf(ssum);

  int b = bs / SS, s = bs - b*SS;
  int h = o >> 4, d = o & 15;
  uint4* og4 = (uint4*)(dst + (((size_t)(b*NH + h)*SS + s)*512 + d*32));
  #pragma unroll
  for(int l=0;l<4;l++){
    uint4 v;
    v.x = (u32)f2bf(a[8*l+0]*inv) | ((u32)f2bf(a[8*l+1]*inv)<<16);
    v.y = (u32)f2bf(a[8*l+2]*inv) | ((u32)f2bf(a[8*l+3]*inv)<<16);
    v.z = (u32)f2bf(a[8*l+4]*inv) | ((u32)f2bf(a[8*l+5]*inv)<<16);
    v.w = (u32)f2bf(a[8*l+6]*inv) | ((u32)f2bf(a[8*l+7]*inv)<<16);
    og4[l] = v;
  }
}

// ---------------- normalize, fp32 flat out (output projection) ---------------
__global__ __launch_bounds__(256) void norm_out(const u16* __restrict__ tmp,
                                                float* __restrict__ dst){
  int t = threadIdx.x;
  int bsl = t >> 7, o = t & 127;
  int bs = blockIdx.x*2 + bsl;

  float a[32];
  float ssum = 1e-8f;
  #pragma unroll
  for(int k=0;k<32;k++){
    a[k] = bf2f(tmp[((size_t)k*768 + bs)*128 + o]);
    ssum = fmaf(a[k], a[k], ssum);
  }
  float inv = 1.0f / sqrtf(ssum);
  float4* og = (float4*)(dst + ((size_t)bs*128 + o)*32);
  #pragma unroll
  for(int l4=0;l4<8;l4++){
    float4 v;
    v.x = a[4*l4+0]*inv; v.y = a[4*l4+1]*inv;
    v.z = a[4*l4+2]*inv; v.w = a[4*l4+3]*inv;
    og[l4] = v;
  }
}

// ---------------- V transpose: vt[bh][dl][x] = vb[bh][x][dl] -----------------
#define TVS 528
__global__ __launch_bounds__(256) void transpose_v(const u16* __restrict__ vb,
                                                   u16* __restrict__ vt){
  __shared__ __align__(16) u16 vl[32*TVS];
  int t = threadIdx.x;
  int xt = blockIdx.x, bh = blockIdx.y;   // xt<12
  const u16* src = vb + ((size_t)bh*SS + xt*32)*512;
  #pragma unroll
  for(int j=0;j<8;j++){
    int f = t + j*256; int row = f>>6, c = (f&63)*8;
    *(uint4*)(vl + row*TVS + c) = *(const uint4*)(src + (size_t)row*512 + c);
  }
  __syncthreads();
  u16* dst = vt + (size_t)bh*512*SS + xt*32;
  #pragma unroll
  for(int j=0;j<8;j++){
    int f = t + j*256; int dl = f>>2, c4 = (f&3)*8;
    u16 tmp[8];
    #pragma unroll
    for(int e=0;e<8;e++) tmp[e] = vl[(c4+e)*TVS + dl];
    *(uint4*)(dst + (size_t)dl*SS + c4) = *(uint4*)tmp;
  }
}

// ---------------- MFMA attention scores, 64-row tiles, XCD + phase-stagger ---
// Per-block pseudo-random rotation of ktl & h order (K-sum order-independent):
// de-phase co-resident blocks so their MFMA bursts interleave on the SIMD.
#define QSTR 264
__global__ __launch_bounds__(256,2) void scores_mfma(const u16* __restrict__ qh,
                                                     const u16* __restrict__ kh,
                                                     float* __restrict__ sc,
                                                     const float* __restrict__ lam){
  __shared__ __align__(16) u16 smem[(64+16)*QSTR];   // 42.24 KB
  u16* qs = smem;
  u16* ks = smem + 64*QSTR;
  int t = threadIdx.x;
  int id  = blockIdx.x;
  int xcd = id & 7;
  int g   = id >> 3;            // 0..287
  int half= g / 144;
  int r9  = g - half*144;
  int bh  = xcd + 8*half;
  int st  = r9 / 24;
  int xt  = r9 - st*24;

  u32 hsh  = (u32)id * 0x9E3779B9u;
  int rot  = (int)(hsh >> 29);        // 0..7 ktl phase
  int hrot = (int)(hsh >> 28) & 1;    // h-half order

  int w = t >> 6, lane = t & 63, q = lane >> 4, mn = lane & 15;
  float lm = lam[0];

  u32 FM[8][4];
  #pragma unroll
  for(int u=0;u<8;u++)
    #pragma unroll
    for(int r=0;r<4;r++) FM[u][r] = MT.v[w][u][q][r];

  f32x4 acc[4][8];
  #pragma unroll
  for(int mi=0;mi<4;mi++)
    #pragma unroll
    for(int u=0;u<8;u++) acc[mi][u] = (f32x4){0.f,0.f,0.f,0.f};

  for(int hi=0; hi<2; hi++){
    int h = hi ^ hrot;
    __syncthreads();
    const u16* qbase = qh + ((size_t)bh*SS + st*64)*512 + h*256;
    const u16* kbase = kh + ((size_t)bh*SS + xt*16)*512 + h*256;
    #pragma unroll
    for(int j=0;j<8;j++){
      int f = t + j*256;
      int row = f>>5, c = (f&31)*8;
      *(uint4*)(qs + row*QSTR + c) = *(const uint4*)(qbase + (size_t)row*512 + c);
    }
    #pragma unroll
    for(int j=0;j<2;j++){
      int f = t + j*256;
      int row = f>>5, c = (f&31)*8;
      *(uint4*)(ks + row*QSTR + c) = *(const uint4*)(kbase + (size_t)row*512 + c);
    }
    __syncthreads();

    for(int ktl=0; ktl<8; ktl++){
      int ke = (ktl + rot) & 7;
      short8 a[4];
      #pragma unroll
      for(int mi=0;mi<4;mi++)
        a[mi] = *(const short8*)(qs + (mi*16+mn)*QSTR + ke*32 + q*8);
      uint4 khd = *(const uint4*)(ks + mn*QSTR + ke*32 + ((q^w)<<3));
      u32 kk[4]  = {khd.x, khd.y, khd.z, khd.w};
      u32 kks[4];
      #pragma unroll
      for(int r=0;r<4;r++) kks[r] = (kk[r]>>16)|(kk[r]<<16);  // hoisted swap
      #pragma unroll
      for(int u=0;u<8;u++){
        union { u32 w32[4]; short8 s; } bf;
        #pragma unroll
        for(int r=0;r<4;r++){
          u32 v = (u & 1) ? kks[r ^ (u>>1)] : kk[r ^ (u>>1)];
          bf.w32[r] = v ^ FM[u][r];
        }
        #pragma unroll
        for(int mi=0;mi<4;mi++)
          acc[mi][u] = __builtin_amdgcn_mfma_f32_16x16x32_bf16(a[mi], bf.s, acc[mi][u], 0, 0, 0);
      }
    }
  }
  __syncthreads();

  // reduce: stride 68 floats (68 mod 32 = 4)
  float* pss = (float*)smem;          // [64][68]
  float* pbb = pss + 64*68;           // [64][68]
  float* ps0 = pbb + 64*68;           // [64][17]

  #pragma unroll
  for(int mi=0;mi<4;mi++){
    #pragma unroll
    for(int rr=0;rr<4;rr++){
      float ssv = 0.f, bbv = 0.f;
      #pragma unroll
      for(int u=0;u<8;u++){
        int c = w*8 + u;
        bool isb = (c==3)||(c==5)||(c==6)||(c==9)||(c==10)||(c==12)||
                   (c==17)||(c==18)||(c==20)||(c==24);
        float v = acc[mi][u][rr];
        ssv = fmaf(v, v, ssv);
        if (isb) bbv = fmaf(v, v, bbv);
      }
      int s = mi*16 + q*4 + rr;
      pss[s*68 + w*16 + mn] = ssv;
      pbb[s*68 + w*16 + mn] = bbv;
      if (w == 0) ps0[s*17 + mn] = acc[mi][0][rr];
    }
  }
  __syncthreads();

  int x = t & 15, s0 = t >> 4;
  #pragma unroll
  for(int ssi=0; ssi<4; ssi++){
    int s = s0 + ssi*16;
    float ss = 1e-8f, bb = 0.f;
    #pragma unroll
    for(int ww=0; ww<4; ww++){
      ss += pss[s*68 + ww*16 + x];
      bb += pbb[s*68 + ww*16 + x];
    }
    float inv = 1.0f / sqrtf(ss);
    float s0v = ps0[s*17+x];
    float score = (s0v*inv + lm*sqrtf(bb*inv*inv + 1e-8f)) * 0.25f;
    sc[((size_t)bh*SS + st*64 + s)*SS + xt*16 + x] = score;
  }
}

// ---------------- fused softmax + P@V (MFMA) + blade-gather epilogue ---------
// dl-split: grid 768, block z∈{0,1} handles 256 of 512 dl-rows (better CU
// balance: 3/CU vs 1.5/CU). kt loop phase-rotated per block.
#define PBS 392   // P LDS row stride u16
#define VSS 40    // Vt chunk LDS row stride u16
__global__ __launch_bounds__(256,2) void pv_mfma(const float* __restrict__ sc,
                                                 const u16* __restrict__ vt,
                                                 u32* __restrict__ xgo){
  __shared__ __align__(16) u16 pb[16*PBS];
  __shared__ __align__(16) u16 vsm[256*VSS];       // overlaid by ot[256][17] f32
  int t = threadIdx.x;
  int id  = blockIdx.x;          // 768 blocks, XCD-affinity
  int xcd = id & 7;
  int rest= id >> 3;             // 0..95
  int z   = rest & 1;
  int g2  = rest >> 1;           // 0..47
  int half= g2 / 24;
  int st  = g2 - half*24;
  int bh  = xcd + 8*half;
  int w = t >> 6, lane = t & 63, q = lane >> 4, mn = lane & 15;

  u32 hsh = (u32)id * 0x9E3779B9u;
  int rotp = (int)(hsh >> 30) * 3;   // 0,3,6,9 phase over 12 kt

  { // softmax prologue
    int row = t >> 4, gg = t & 15;
    const float* srow = sc + ((size_t)bh*SS + st*16 + row)*SS;
    float v[24];
    float mx = -1e30f;
    #pragma unroll
    for(int k2=0;k2<24;k2++){ v[k2] = srow[gg + k2*16]; mx = fmaxf(mx, v[k2]); }
    #pragma unroll
    for(int off=8; off; off>>=1) mx = fmaxf(mx, __shfl_xor(mx, off));
    float sum = 0.f;
    #pragma unroll
    for(int k2=0;k2<24;k2++){ v[k2] = __expf(v[k2]-mx); sum += v[k2]; }
    #pragma unroll
    for(int off=8; off; off>>=1) sum += __shfl_xor(sum, off);
    float inv = 1.f/sum;
    #pragma unroll
    for(int k2=0;k2<24;k2++) pb[row*PBS + gg + k2*16] = f2bf(v[k2]*inv);
  }

  f32x4 acc[4];
  #pragma unroll
  for(int mt=0;mt<4;mt++) acc[mt] = (f32x4){0.f,0.f,0.f,0.f};

  const u16* vtb = vt + (size_t)bh*512*SS + (size_t)z*256*SS;
  for(int kt=0; kt<12; kt++){
    int ke = kt + rotp; if (ke >= 12) ke -= 12;
    __syncthreads();
    #pragma unroll
    for(int j=0;j<4;j++){
      int f = t + j*256;
      int dl = f>>2, c4 = (f&3)*8;
      *(uint4*)(vsm + dl*VSS + c4) = *(const uint4*)(vtb + (size_t)dl*SS + ke*32 + c4);
    }
    __syncthreads();
    short8 b = *(const short8*)(pb + mn*PBS + ke*32 + q*8);
    #pragma unroll
    for(int mt=0;mt<4;mt++){
      short8 a = *(const short8*)(vsm + ((w*4+mt)*16 + mn)*VSS + q*8);
      acc[mt] = __builtin_amdgcn_mfma_f32_16x16x32_bf16(a, b, acc[mt], 0, 0, 0);
    }
  }
  __syncthreads();

  float* ot = (float*)vsm;    // [256][17], row = l*8 + d_loc
  #pragma unroll
  for(int mt=0;mt<4;mt++)
    #pragma unroll
    for(int rr=0;rr<4;rr++){
      int dl = (w*4+mt)*16 + q*4 + rr;      // local 0..255
      int row = ((dl & 31) << 3) | (dl >> 5);
      ot[row*17 + mn] = acc[mt][rr];
    }
  __syncthreads();

  int b = bh >> 3, h = bh & 7;
  int bs_base = b*SS + st*16;
  const int SVc[6] = {0,1,2,4,8,16};
  #pragma unroll 4
  for(int it=0; it<48; it++){
    int idx = it*256 + t;
    int dpl = idx & 3;
    int s   = (idx >> 2) & 15;
    int jl  = idx >> 6;          // 0..191
    int jp  = jl >> 5;
    int l   = jl & 31;
    int k   = SVc[jp] ^ l;
    float sg = GPS.v[SVc[jp]][l];
    float v0 = sg * ot[(l*8 + dpl*2    )*17 + s];
    float v1 = sg * ot[(l*8 + dpl*2 + 1)*17 + s];
    u32 pk = (u32)f2bf(v0) | ((u32)f2bf(v1) << 16);
    xgo[((size_t)k*768 + bs_base + s)*384 + (size_t)(jp*64 + h*8 + z*4 + dpl)] = pk;
  }
}

// ---------------- launch ------------------------------------------------------
extern "C" void kernel_launch(void* const* d_in, const int* in_sizes, int n_in,
                              void* d_out, int out_size, void* d_ws, size_t ws_size,
                              hipStream_t stream) {
  const float* x   = (const float*)d_in[0];
  const float* wq  = (const float*)d_in[1];
  const float* wk  = (const float*)d_in[2];
  const float* wv  = (const float*)d_in[3];
  const float* wo  = (const float*)d_in[4];
  const float* lam = (const float*)d_in[5];
  float* out = (float*)d_out;

  char* ws = (char*)d_ws;
  size_t off = 0;
  u16*   wpk2 = (u16*)(ws + off); off += (size_t)4*98304*2;           // 0.79 MB
  u16*   xg   = (u16*)(ws + off); off += (size_t)32*768*768*2;        // 36 MB
  u16*   tmp3 = (u16*)(ws + off); off += (size_t)3*32*768*128*2;      // 18.9 MB
  u16*   vt   = tmp3;                                  // 6.29 MB overlay
  float* sc   = (float*)((char*)tmp3 + 6291456);       // 9.4 MB overlay (after norm3)
  u16*   qhb  = (u16*)(ws + off); off += (size_t)NBH*SS*512*2;        // 6.29 MB
  u16*   khb  = (u16*)(ws + off); off += (size_t)NBH*SS*512*2;
  u16*   vb   = (u16*)(ws + off); off += (size_t)NBH*SS*512*2;

  gather_k<<<dim3(384,2),256,0,stream>>>(x, xg, wq, wk, wv, wo, wpk2);
  gemm_proj<<<dim3(6,32,3),256,0,stream>>>(xg, wpk2, tmp3);
  norm3<<<dim3(384,3),256,0,stream>>>(tmp3, qhb, khb, vb);
  transpose_v<<<dim3(12,16),256,0,stream>>>(vb, vt);

  scores_mfma<<<2304,256,0,stream>>>(qhb, khb, sc, lam);
  pv_mfma<<<768,256,0,stream>>>(sc, vt, (u32*)xg);     // writes xgo into xg

  gemm_proj<<<dim3(6,32,1),256,0,stream>>>(xg, wpk2 + (size_t)3*98304, tmp3);
  norm_out<<<384,256,0,stream>>>(tmp3, out);
}

// Round 9
// 224.679 us; speedup vs baseline: 1.1418x; 1.1418x over previous
//
#include <hip/hip_runtime.h>
#include <math.h>

// Problem constants
#define BB    2
#define SS    384
#define DD    128
#define NH    8
#define HDIM  16
#define NBH   16      // B*H
#define BS    768     // B*S

typedef unsigned int   u32;
typedef unsigned short u16;
typedef __attribute__((ext_vector_type(8))) short short8;
typedef __attribute__((ext_vector_type(4))) float f32x4;

// ---------------- compile-time Cl(4,1) geometric-product sign table ----------
struct SignTab { float v[32][32]; };
constexpr int popcnt32c(int x){ int c=0; for(int i=0;i<32;i++) c += (x>>i)&1; return c; }
constexpr int signgp_int(int a, int b){
  int swaps=0; int aa=a>>1;
  while(aa){ swaps += popcnt32c(aa & b); aa >>= 1; }
  int s = (swaps & 1) ? -1 : 1;
  if ((a & b) & 16) s = -s;   // e5 (bit 4) squares to -1
  return s;
}
constexpr SignTab make_signs(){
  SignTab t{};
  for(int a=0;a<32;a++) for(int b=0;b<32;b++)
    t.v[a][b] = (float)signgp_int(a,b);
  return t;
}
constexpr SignTab GPS = make_signs();

// Sign-bit XOR masks for scores B fragment, blade c=(w<<3)|u.
struct MaskTab { u32 v[4][8][4][4]; };
constexpr MaskTab mkmask(){
  MaskTab t{};
  for(int w=0;w<4;w++) for(int u=0;u<8;u++) for(int q=0;q<4;q++) for(int r=0;r<4;r++){
    u32 m = 0;
    for(int h=0;h<2;h++){
      int j = 2*r + h;
      int i = (q<<3) | j;
      int c = (w<<3) | u;
      if (signgp_int(i, i^c) < 0) m |= (h ? 0x80000000u : 0x8000u);
    }
    t.v[w][u][q][r] = m;
  }
  return t;
}
constexpr MaskTab MT = mkmask();

// Per-(jp,k) A-tile sign for the projection GEMM: sign(SV[jp], SV[jp]^k) < 0 ?
struct PMask { u32 v[6][32]; };
constexpr PMask mkpmask(){
  PMask t{};
  const int SV[6] = {0,1,2,4,8,16};
  for(int jp=0;jp<6;jp++) for(int k=0;k<32;k++)
    t.v[jp][k] = (signgp_int(SV[jp], SV[jp]^k) < 0) ? 0x80008000u : 0u;
  return t;
}
constexpr PMask PM = mkpmask();

__device__ __forceinline__ u16 f2bf(float f){   // round-to-nearest-even
  u32 x = __float_as_uint(f);
  return (u16)((x + 0x7FFFu + ((x>>16)&1u)) >> 16);
}
__device__ __forceinline__ float bf2f(u16 h){
  return __uint_as_float(((u32)h) << 16);
}

// ---------------- blade transpose (y=0) + weight repack (y=1) ----------------
// xT[b][r] = bf16(x[r][b]), r = bs*128+i (98304 rows).  6.3 MB total.
// repack: wpk2[p][o][jp*128+i] = bf16(w_p[o,i,SV[jp]])
__global__ __launch_bounds__(256) void transpose_x(const float* __restrict__ src,
                                                   u16* __restrict__ xT,
                                                   const float* __restrict__ wq,
                                                   const float* __restrict__ wk,
                                                   const float* __restrict__ wv,
                                                   const float* __restrict__ wo,
                                                   u16* __restrict__ wpk2){
  if (blockIdx.y == 1){
    int idx = blockIdx.x*256 + threadIdx.x;      // 0..98303
    int o   = idx / 768;
    int rem = idx - o*768;
    int jp  = rem >> 7;
    int i   = rem & 127;
    const int SV[6] = {0,1,2,4,8,16};
    const float* ww[4] = {wq, wk, wv, wo};
    #pragma unroll
    for(int p=0;p<4;p++)
      wpk2[p*98304 + idx] = f2bf(ww[p][(o*128 + i)*32 + SV[jp]]);
    return;
  }

  __shared__ __align__(16) u16 xb[32*264];   // [b][r] tile, row stride 264
  int t = threadIdx.x;
  int r0 = blockIdx.x*256;

  const float4* s4 = (const float4*)(src + (size_t)r0*32);
  #pragma unroll
  for(int j=0;j<8;j++){
    int f = t + j*256;          // 2048 float4 = 256 r x 32 b
    int rr = f >> 3;
    int bc = (f & 7)*4;
    float4 v = s4[f];
    xb[(bc+0)*264 + rr] = f2bf(v.x);
    xb[(bc+1)*264 + rr] = f2bf(v.y);
    xb[(bc+2)*264 + rr] = f2bf(v.z);
    xb[(bc+3)*264 + rr] = f2bf(v.w);
  }
  __syncthreads();
  #pragma unroll
  for(int j=0;j<4;j++){
    int f = t + j*256;          // 1024 uint4 = 32 b x 32 chunks(8 r)
    int b = f >> 5;
    int ch = f & 31;
    uint4 v = *(const uint4*)(xb + b*264 + ch*8);
    *(uint4*)(xT + (size_t)b*98304 + r0 + ch*8) = v;
  }
}

// ---------------- projection GEMM (A = sign-folded blade-transposed view) ----
// Block (Mt, k, z): C(128 bs x 128 o) over K=768; kt -> jp=kt>>2, A slab =
// xT[SV[jp]^k] with per-(jp,k) sign XOR applied at staging (PM table).
#define LSTR 40
__global__ __launch_bounds__(256) void gemm_proj(const u16* __restrict__ Asrc,
                                                 const u16* __restrict__ wpkA,
                                                 u16* __restrict__ tmpA,
                                                 int poff){
  __shared__ __align__(16) u16 As[128*LSTR];
  __shared__ __align__(16) u16 Bs[128*LSTR];
  int t = threadIdx.x;
  int Mt = blockIdx.x, k = blockIdx.y;
  const u16* wpk = wpkA + (size_t)(poff + blockIdx.z)*98304;
  u16* tmp = tmpA + (size_t)blockIdx.z*32*768*128;

  int w = t >> 6, lane = t & 63;
  int q = lane >> 4, n16 = lane & 15;
  int wm = w >> 1, wn = w & 1;

  f32x4 acc[4][4];
  #pragma unroll
  for(int a=0;a<4;a++)
    #pragma unroll
    for(int b=0;b<4;b++) acc[a][b] = (f32x4){0.f,0.f,0.f,0.f};

  int r0 = t>>2, c0 = (t&3)*8;
  int r1 = (t+256)>>2, c1 = ((t+256)&3)*8;

  const int SV[6] = {0,1,2,4,8,16};
  // A slab pointer + sign mask for a given kt
  #define APTR(kt_) (Asrc + ((size_t)(SV[(kt_)>>2]^k)*768 + Mt*128)*128 + ((kt_)&3)*32)
  #define AMSK(kt_) (PM.v[(kt_)>>2][k])

  uint4 pa0, pa1, pb0, pb1;
  {
    const u16* ap = APTR(0);
    u32 am = AMSK(0);
    pa0 = *(const uint4*)(ap + (size_t)r0*128 + c0);
    pa1 = *(const uint4*)(ap + (size_t)r1*128 + c1);
    pa0.x ^= am; pa0.y ^= am; pa0.z ^= am; pa0.w ^= am;
    pa1.x ^= am; pa1.y ^= am; pa1.z ^= am; pa1.w ^= am;
    pb0 = *(const uint4*)(wpk + (size_t)r0*768 + c0);
    pb1 = *(const uint4*)(wpk + (size_t)r1*768 + c1);
  }

  for(int kt=0; kt<24; kt++){
    __syncthreads();
    *(uint4*)(As + r0*LSTR + c0) = pa0;
    *(uint4*)(As + r1*LSTR + c1) = pa1;
    *(uint4*)(Bs + r0*LSTR + c0) = pb0;
    *(uint4*)(Bs + r1*LSTR + c1) = pb1;
    __syncthreads();
    if (kt < 23){
      int kn = (kt+1)*32;
      const u16* ap = APTR(kt+1);
      u32 am = AMSK(kt+1);
      pa0 = *(const uint4*)(ap + (size_t)r0*128 + c0);
      pa1 = *(const uint4*)(ap + (size_t)r1*128 + c1);
      pa0.x ^= am; pa0.y ^= am; pa0.z ^= am; pa0.w ^= am;
      pa1.x ^= am; pa1.y ^= am; pa1.z ^= am; pa1.w ^= am;
      pb0 = *(const uint4*)(wpk + (size_t)r0*768 + kn + c0);
      pb1 = *(const uint4*)(wpk + (size_t)r1*768 + kn + c1);
    }
    short8 a[4], b[4];
    #pragma unroll
    for(int mi=0;mi<4;mi++)
      a[mi] = *(const short8*)(As + (wm*64 + mi*16 + n16)*LSTR + q*8);
    #pragma unroll
    for(int ni=0;ni<4;ni++)
      b[ni] = *(const short8*)(Bs + (wn*64 + ni*16 + n16)*LSTR + q*8);
    #pragma unroll
    for(int mi=0;mi<4;mi++)
      #pragma unroll
      for(int ni=0;ni<4;ni++)
        acc[mi][ni] = __builtin_amdgcn_mfma_f32_16x16x32_bf16(a[mi], b[ni], acc[mi][ni], 0,0,0);
  }
  #undef APTR
  #undef AMSK

  #pragma unroll
  for(int mi=0;mi<4;mi++){
    #pragma unroll
    for(int r=0;r<4;r++){
      int m = Mt*128 + wm*64 + mi*16 + q*4 + r;
      #pragma unroll
      for(int ni=0;ni<4;ni++){
        int n = wn*64 + ni*16 + n16;
        tmp[((size_t)k*768 + m)*128 + n] = f2bf(acc[mi][ni][r]);
      }
    }
  }
}

// ---------------- normalize + head-split for Q,K,V (one dispatch) ------------
__global__ __launch_bounds__(256) void norm3(const u16* __restrict__ tmpA,
                                             u16* __restrict__ qhb,
                                             u16* __restrict__ khb,
                                             u16* __restrict__ vbb){
  int z = blockIdx.y;
  const u16* tmp = tmpA + (size_t)z*32*768*128;
  u16* dst = (z==0)?qhb:(z==1)?khb:vbb;
  int t = threadIdx.x;
  int bsl = t >> 7, o = t & 127;
  int bs = blockIdx.x*2 + bsl;

  float a[32];
  float ssum = 1e-8f;
  #pragma unroll
  for(int k=0;k<32;k++){
    a[k] = bf2f(tmp[((size_t)k*768 + bs)*128 + o]);
    ssum = fmaf(a[k], a[k], ssum);
  }
  float inv = 1.0f / sqrtf(ssum);

  int b = bs / SS, s = bs - b*SS;
  int h = o >> 4, d = o & 15;
  uint4* og4 = (uint4*)(dst + (((size_t)(b*NH + h)*SS + s)*512 + d*32));
  #pragma unroll
  for(int l=0;l<4;l++){
    uint4 v;
    v.x = (u32)f2bf(a[8*l+0]*inv) | ((u32)f2bf(a[8*l+1]*inv)<<16);
    v.y = (u32)f2bf(a[8*l+2]*inv) | ((u32)f2bf(a[8*l+3]*inv)<<16);
    v.z = (u32)f2bf(a[8*l+4]*inv) | ((u32)f2bf(a[8*l+5]*inv)<<16);
    v.w = (u32)f2bf(a[8*l+6]*inv) | ((u32)f2bf(a[8*l+7]*inv)<<16);
    og4[l] = v;
  }
}

// ---------------- normalize, fp32 flat out (output projection) ---------------
__global__ __launch_bounds__(256) void norm_out(const u16* __restrict__ tmp,
                                                float* __restrict__ dst){
  int t = threadIdx.x;
  int bsl = t >> 7, o = t & 127;
  int bs = blockIdx.x*2 + bsl;

  float a[32];
  float ssum = 1e-8f;
  #pragma unroll
  for(int k=0;k<32;k++){
    a[k] = bf2f(tmp[((size_t)k*768 + bs)*128 + o]);
    ssum = fmaf(a[k], a[k], ssum);
  }
  float inv = 1.0f / sqrtf(ssum);
  float4* og = (float4*)(dst + ((size_t)bs*128 + o)*32);
  #pragma unroll
  for(int l4=0;l4<8;l4++){
    float4 v;
    v.x = a[4*l4+0]*inv; v.y = a[4*l4+1]*inv;
    v.z = a[4*l4+2]*inv; v.w = a[4*l4+3]*inv;
    og[l4] = v;
  }
}

// ---------------- V transpose: vt[bh][dl][x] = vb[bh][x][dl] -----------------
#define TVS 528
__global__ __launch_bounds__(256) void transpose_v(const u16* __restrict__ vb,
                                                   u16* __restrict__ vt){
  __shared__ __align__(16) u16 vl[32*TVS];
  int t = threadIdx.x;
  int xt = blockIdx.x, bh = blockIdx.y;   // xt<12
  const u16* src = vb + ((size_t)bh*SS + xt*32)*512;
  #pragma unroll
  for(int j=0;j<8;j++){
    int f = t + j*256; int row = f>>6, c = (f&63)*8;
    *(uint4*)(vl + row*TVS + c) = *(const uint4*)(src + (size_t)row*512 + c);
  }
  __syncthreads();
  u16* dst = vt + (size_t)bh*512*SS + xt*32;
  #pragma unroll
  for(int j=0;j<8;j++){
    int f = t + j*256; int dl = f>>2, c4 = (f&3)*8;
    u16 tmp[8];
    #pragma unroll
    for(int e=0;e<8;e++) tmp[e] = vl[(c4+e)*TVS + dl];
    *(uint4*)(dst + (size_t)dl*SS + c4) = *(uint4*)tmp;
  }
}

// ---------------- MFMA attention scores (R8: XCD-affinity + stagger) ---------
#define QSTR 264
__global__ __launch_bounds__(256,2) void scores_mfma(const u16* __restrict__ qh,
                                                     const u16* __restrict__ kh,
                                                     float* __restrict__ sc,
                                                     const float* __restrict__ lam){
  __shared__ __align__(16) u16 smem[(64+16)*QSTR];   // 42.24 KB
  u16* qs = smem;
  u16* ks = smem + 64*QSTR;
  int t = threadIdx.x;
  int id  = blockIdx.x;
  int xcd = id & 7;
  int g   = id >> 3;            // 0..287
  int half= g / 144;
  int r9  = g - half*144;
  int bh  = xcd + 8*half;
  int st  = r9 / 24;
  int xt  = r9 - st*24;

  u32 hsh  = (u32)id * 0x9E3779B9u;
  int rot  = (int)(hsh >> 29);        // 0..7 ktl phase
  int hrot = (int)(hsh >> 28) & 1;    // h-half order

  int w = t >> 6, lane = t & 63, q = lane >> 4, mn = lane & 15;
  float lm = lam[0];

  u32 FM[8][4];
  #pragma unroll
  for(int u=0;u<8;u++)
    #pragma unroll
    for(int r=0;r<4;r++) FM[u][r] = MT.v[w][u][q][r];

  f32x4 acc[4][8];
  #pragma unroll
  for(int mi=0;mi<4;mi++)
    #pragma unroll
    for(int u=0;u<8;u++) acc[mi][u] = (f32x4){0.f,0.f,0.f,0.f};

  for(int hi=0; hi<2; hi++){
    int h = hi ^ hrot;
    __syncthreads();
    const u16* qbase = qh + ((size_t)bh*SS + st*64)*512 + h*256;
    const u16* kbase = kh + ((size_t)bh*SS + xt*16)*512 + h*256;
    #pragma unroll
    for(int j=0;j<8;j++){
      int f = t + j*256;
      int row = f>>5, c = (f&31)*8;
      *(uint4*)(qs + row*QSTR + c) = *(const uint4*)(qbase + (size_t)row*512 + c);
    }
    #pragma unroll
    for(int j=0;j<2;j++){
      int f = t + j*256;
      int row = f>>5, c = (f&31)*8;
      *(uint4*)(ks + row*QSTR + c) = *(const uint4*)(kbase + (size_t)row*512 + c);
    }
    __syncthreads();

    for(int ktl=0; ktl<8; ktl++){
      int ke = (ktl + rot) & 7;
      short8 a[4];
      #pragma unroll
      for(int mi=0;mi<4;mi++)
        a[mi] = *(const short8*)(qs + (mi*16+mn)*QSTR + ke*32 + q*8);
      uint4 khd = *(const uint4*)(ks + mn*QSTR + ke*32 + ((q^w)<<3));
      u32 kk[4]  = {khd.x, khd.y, khd.z, khd.w};
      u32 kks[4];
      #pragma unroll
      for(int r=0;r<4;r++) kks[r] = (kk[r]>>16)|(kk[r]<<16);  // hoisted swap
      #pragma unroll
      for(int u=0;u<8;u++){
        union { u32 w32[4]; short8 s; } bf;
        #pragma unroll
        for(int r=0;r<4;r++){
          u32 v = (u & 1) ? kks[r ^ (u>>1)] : kk[r ^ (u>>1)];
          bf.w32[r] = v ^ FM[u][r];
        }
        #pragma unroll
        for(int mi=0;mi<4;mi++)
          acc[mi][u] = __builtin_amdgcn_mfma_f32_16x16x32_bf16(a[mi], bf.s, acc[mi][u], 0, 0, 0);
      }
    }
  }
  __syncthreads();

  float* pss = (float*)smem;          // [64][68]
  float* pbb = pss + 64*68;           // [64][68]
  float* ps0 = pbb + 64*68;           // [64][17]

  #pragma unroll
  for(int mi=0;mi<4;mi++){
    #pragma unroll
    for(int rr=0;rr<4;rr++){
      float ssv = 0.f, bbv = 0.f;
      #pragma unroll
      for(int u=0;u<8;u++){
        int c = w*8 + u;
        bool isb = (c==3)||(c==5)||(c==6)||(c==9)||(c==10)||(c==12)||
                   (c==17)||(c==18)||(c==20)||(c==24);
        float v = acc[mi][u][rr];
        ssv = fmaf(v, v, ssv);
        if (isb) bbv = fmaf(v, v, bbv);
      }
      int s = mi*16 + q*4 + rr;
      pss[s*68 + w*16 + mn] = ssv;
      pbb[s*68 + w*16 + mn] = bbv;
      if (w == 0) ps0[s*17 + mn] = acc[mi][0][rr];
    }
  }
  __syncthreads();

  int x = t & 15, s0 = t >> 4;
  #pragma unroll
  for(int ssi=0; ssi<4; ssi++){
    int s = s0 + ssi*16;
    float ss = 1e-8f, bb = 0.f;
    #pragma unroll
    for(int ww=0; ww<4; ww++){
      ss += pss[s*68 + ww*16 + x];
      bb += pbb[s*68 + ww*16 + x];
    }
    float inv = 1.0f / sqrtf(ss);
    float s0v = ps0[s*17+x];
    float score = (s0v*inv + lm*sqrtf(bb*inv*inv + 1e-8f)) * 0.25f;
    sc[((size_t)bh*SS + st*64 + s)*SS + xt*16 + x] = score;
  }
}

// ---------------- fused softmax + P@V (MFMA), omT epilogue -------------------
// dl-split grid 768. Epilogue writes omT[l][bs][o=h*16+d] bf16 (6.3 MB) —
// the blade-gather is now folded into the output gemm's A staging.
#define PBS 392   // P LDS row stride u16
#define VSS 40    // Vt chunk LDS row stride u16
__global__ __launch_bounds__(256,2) void pv_mfma(const float* __restrict__ sc,
                                                 const u16* __restrict__ vt,
                                                 u16* __restrict__ omT){
  __shared__ __align__(16) u16 pb[16*PBS];
  __shared__ __align__(16) u16 vsm[256*VSS];       // overlaid by ot[256][17] f32
  int t = threadIdx.x;
  int id  = blockIdx.x;          // 768 blocks, XCD-affinity
  int xcd = id & 7;
  int rest= id >> 3;             // 0..95
  int z   = rest & 1;
  int g2  = rest >> 1;           // 0..47
  int half= g2 / 24;
  int st  = g2 - half*24;
  int bh  = xcd + 8*half;
  int w = t >> 6, lane = t & 63, q = lane >> 4, mn = lane & 15;

  u32 hsh = (u32)id * 0x9E3779B9u;
  int rotp = (int)(hsh >> 30) * 3;   // 0,3,6,9 phase over 12 kt

  { // softmax prologue
    int row = t >> 4, gg = t & 15;
    const float* srow = sc + ((size_t)bh*SS + st*16 + row)*SS;
    float v[24];
    float mx = -1e30f;
    #pragma unroll
    for(int k2=0;k2<24;k2++){ v[k2] = srow[gg + k2*16]; mx = fmaxf(mx, v[k2]); }
    #pragma unroll
    for(int off=8; off; off>>=1) mx = fmaxf(mx, __shfl_xor(mx, off));
    float sum = 0.f;
    #pragma unroll
    for(int k2=0;k2<24;k2++){ v[k2] = __expf(v[k2]-mx); sum += v[k2]; }
    #pragma unroll
    for(int off=8; off; off>>=1) sum += __shfl_xor(sum, off);
    float inv = 1.f/sum;
    #pragma unroll
    for(int k2=0;k2<24;k2++) pb[row*PBS + gg + k2*16] = f2bf(v[k2]*inv);
  }

  f32x4 acc[4];
  #pragma unroll
  for(int mt=0;mt<4;mt++) acc[mt] = (f32x4){0.f,0.f,0.f,0.f};

  const u16* vtb = vt + (size_t)bh*512*SS + (size_t)z*256*SS;
  for(int kt=0; kt<12; kt++){
    int ke = kt + rotp; if (ke >= 12) ke -= 12;
    __syncthreads();
    #pragma unroll
    for(int j=0;j<4;j++){
      int f = t + j*256;
      int dl = f>>2, c4 = (f&3)*8;
      *(uint4*)(vsm + dl*VSS + c4) = *(const uint4*)(vtb + (size_t)dl*SS + ke*32 + c4);
    }
    __syncthreads();
    short8 b = *(const short8*)(pb + mn*PBS + ke*32 + q*8);
    #pragma unroll
    for(int mt=0;mt<4;mt++){
      short8 a = *(const short8*)(vsm + ((w*4+mt)*16 + mn)*VSS + q*8);
      acc[mt] = __builtin_amdgcn_mfma_f32_16x16x32_bf16(a, b, acc[mt], 0, 0, 0);
    }
  }
  __syncthreads();

  float* ot = (float*)vsm;    // [256][17], row = l*8 + d_loc
  #pragma unroll
  for(int mt=0;mt<4;mt++)
    #pragma unroll
    for(int rr=0;rr<4;rr++){
      int dl = (w*4+mt)*16 + q*4 + rr;      // local = (d&7)*32 + l
      int row = ((dl & 31) << 3) | (dl >> 5);
      ot[row*17 + mn] = acc[mt][rr];
    }
  __syncthreads();

  int b = bh >> 3, h = bh & 7;
  int bs_base = b*SS + st*16;
  #pragma unroll
  for(int j=0;j<2;j++){
    int idx = t + j*256;        // 0..511 = 32 l x 16 s
    int s = idx & 15;
    int l = idx >> 4;
    u16 t8[8];
    #pragma unroll
    for(int e=0;e<8;e++) t8[e] = f2bf(ot[(l*8+e)*17 + s]);
    *(uint4*)(omT + ((size_t)l*768 + bs_base + s)*128 + h*16 + z*8) = *(uint4*)t8;
  }
}

// ---------------- launch ------------------------------------------------------
extern "C" void kernel_launch(void* const* d_in, const int* in_sizes, int n_in,
                              void* d_out, int out_size, void* d_ws, size_t ws_size,
                              hipStream_t stream) {
  const float* x   = (const float*)d_in[0];
  const float* wq  = (const float*)d_in[1];
  const float* wk  = (const float*)d_in[2];
  const float* wv  = (const float*)d_in[3];
  const float* wo  = (const float*)d_in[4];
  const float* lam = (const float*)d_in[5];
  float* out = (float*)d_out;

  char* ws = (char*)d_ws;
  size_t off = 0;
  u16*   wpk2 = (u16*)(ws + off); off += (size_t)4*98304*2;           // 0.79 MB
  u16*   xT   = (u16*)(ws + off); off += (size_t)32*98304*2;          // 6.29 MB
  u16*   omT  = xT;                    // overlay: xT dead after QKV gemm
  u16*   tmp3 = (u16*)(ws + off); off += (size_t)3*32*768*128*2;      // 18.9 MB
  u16*   vt   = tmp3;                                  // 6.29 MB overlay
  float* sc   = (float*)((char*)tmp3 + 6291456);       // 9.4 MB overlay
  u16*   qhb  = (u16*)(ws + off); off += (size_t)NBH*SS*512*2;        // 6.29 MB
  u16*   khb  = (u16*)(ws + off); off += (size_t)NBH*SS*512*2;
  u16*   vb   = (u16*)(ws + off); off += (size_t)NBH*SS*512*2;
  // total ~45 MB

  transpose_x<<<dim3(384,2),256,0,stream>>>(x, xT, wq, wk, wv, wo, wpk2);
  gemm_proj<<<dim3(6,32,3),256,0,stream>>>(xT, wpk2, tmp3, 0);
  norm3<<<dim3(384,3),256,0,stream>>>(tmp3, qhb, khb, vb);
  transpose_v<<<dim3(12,16),256,0,stream>>>(vb, vt);

  scores_mfma<<<2304,256,0,stream>>>(qhb, khb, sc, lam);
  pv_mfma<<<768,256,0,stream>>>(sc, vt, omT);

  gemm_proj<<<dim3(6,32,1),256,0,stream>>>(omT, wpk2, tmp3, 3);
  norm_out<<<384,256,0,stream>>>(tmp3, out);
}